// Round 8
// baseline (393.017 us; speedup 1.0000x reference)
//
#include <hip/hip_runtime.h>

#define S 512
#define B 1024
#define K 48
#define NCH 16            // chains per block = MFMA N
#define NBLK (B / NCH)    // 64 blocks
#define PF 8              // LDS ring depth (timesteps)
#define SLOT_SZ 3328      // 3*1024 em + 256 mask
#define LN2 0.6931471805599453f
#define LOG2E 1.4426950408889634f

typedef float f4 __attribute__((ext_vector_type(4)));
typedef __bf16 b8 __attribute__((ext_vector_type(8)));
union BU { b8 v; unsigned u[4]; };

__device__ __forceinline__ f4 mfma32(b8 a, b8 b, f4 c) {
    return __builtin_amdgcn_mfma_f32_16x16x32_bf16(a, b, c, 0, 0, 0);
}
// async global->LDS: dest = ldsbase + lane*size (unsinkable, no VGPR result)
__device__ __forceinline__ void stage16(const void* g, void* l) {
    __builtin_amdgcn_global_load_lds(
        (const __attribute__((address_space(1))) void*)g,
        (__attribute__((address_space(3))) void*)l, 16, 0, 0);
}
__device__ __forceinline__ void stage4(const void* g, void* l) {
    __builtin_amdgcn_global_load_lds(
        (const __attribute__((address_space(1))) void*)g,
        (__attribute__((address_space(3))) void*)l, 4, 0, 0);
}

__global__ void __launch_bounds__(64) zero_out(float* o) {
    if (threadIdx.x == 0) o[0] = 0.f;
}

__global__ void __launch_bounds__(64) crf_kernel(
    const float* __restrict__ em, const int* __restrict__ tags,
    const int* __restrict__ mask, const float* __restrict__ trans,
    const float* __restrict__ start_tr, const float* __restrict__ end_tr,
    float* __restrict__ out)
{
    const int lane = threadIdx.x;
    const int c    = lane & 15;     // chain within block / MFMA column
    const int g    = lane >> 4;     // 4-row group
    const int bb   = blockIdx.x * NCH;
    const int b    = bb + c;

    __shared__ __align__(16) char ldsbuf[PF][SLOT_SZ];

    // ---------------- score: lane = (chain c, t-quarter g) ----------------
    float sc = 0.f;
    int   mc = 0;
    {
        int tagp = 0;
        if (g > 0) tagp = tags[(128 * g - 1) * B + b];
        #pragma unroll 4
        for (int i = 0; i < 128; ++i) {
            int t   = 128 * g + i;
            int tag = tags[t * B + b];
            int mk  = mask[t * B + b];
            mc += mk;
            if (t == 0) {
                sc += start_tr[tag] + em[(size_t)b * K + tag];
            } else {
                float add = trans[tagp * K + tag] + em[((size_t)t * B + b) * K + tag];
                sc += mk ? add : 0.f;
            }
            tagp = tag;
        }
        sc += __shfl_xor(sc, 16);  sc += __shfl_xor(sc, 32);
        mc += __shfl_xor(mc, 16);  mc += __shfl_xor(mc, 32);
        int lt = mc - 1; if (lt < 0) lt += S;
        sc += end_tr[tags[lt * B + b]];        // replicated over g
    }

    // ---------------- partition: MFMA forward algorithm ----------------
    // A[row=16tr+c][k] = exp(trans[k][16tr+c]); k-map verified R6 (absmax 0)
    BU Afr[3][2];
    #pragma unroll
    for (int tr = 0; tr < 3; ++tr)
        #pragma unroll
        for (int kc = 0; kc < 2; ++kc)
            #pragma unroll
            for (int e = 0; e < 8; ++e) {
                int kk = 32 * kc + 16 * (e >> 2) + 4 * g + (e & 3);
                float v = (kk < K) ? __expf(trans[kk * K + 16 * tr + c]) : 0.f;
                Afr[tr][kc].v[e] = (__bf16)v;
            }

    // B init: alpha0[k] = exp(start[k] + em[0][b][k])
    BU Bf[2];
    #pragma unroll
    for (int kc = 0; kc < 2; ++kc)
        #pragma unroll
        for (int e = 0; e < 8; ++e) {
            int kk = 32 * kc + 16 * (e >> 2) + 4 * g + (e & 3);
            float v = (kk < K) ? __expf(start_tr[kk] + em[(size_t)b * K + kk]) : 1.f;
            Bf[kc].v[e] = (__bf16)v;
        }

// stage time t_ into slot s_ : 3x16B em (chunks k=0..15,16..31,32..47) + mask
#define STAGE(t_, s_)                                                           \
    {                                                                           \
        const float* rp_ = em + ((size_t)(t_) * B + bb + c) * K + 4 * g;        \
        stage16(rp_,      &ldsbuf[s_][0]);                                      \
        stage16(rp_ + 16, &ldsbuf[s_][1024]);                                   \
        stage16(rp_ + 32, &ldsbuf[s_][2048]);                                   \
        stage4(mask + (t_) * B + bb + c, &ldsbuf[s_][3072]);                    \
    }

    // prologue: fill slots for t = 1..8 (slot = t&7): issue order 1,2,...,7,8
    #pragma unroll
    for (int i = 0; i < PF; ++i) STAGE(1 + i, (1 + i) & 7);

    // slot 1 (t=1) is the oldest 4 of 32 outstanding -> vmcnt(28)
    asm volatile("s_waitcnt vmcnt(28)" ::: "memory");
    __builtin_amdgcn_sched_barrier(0);
    f4 eem[3];
    {
        f4 i0 = *(const f4*)&ldsbuf[1][lane * 16];
        f4 i1 = *(const f4*)&ldsbuf[1][1024 + lane * 16];
        f4 i2 = *(const f4*)&ldsbuf[1][2048 + lane * 16];
        #pragma unroll
        for (int e = 0; e < 4; ++e) {
            eem[0][e] = exp2f(i0[e] * LOG2E);
            eem[1][e] = exp2f(i1[e] * LOG2E);
            eem[2][e] = exp2f(i2[e] * LOG2E);
        }
    }

    int   offc  = 0;     // per-chain log2 offset (replicated over g)
    int   n_cur = 0;     // pending renorm for the keep-old path
    float rshfl = 0.f;   // stale-alpha renorm sample

// s_ = t&7 (compile-time), t_ = current step
#define STEP(s_, t_)                                                            \
    {                                                                           \
        /* slot (t+1)'s 4 loads were issued 7 steps ago -> 24 newer */          \
        asm volatile("s_waitcnt vmcnt(24)" ::: "memory");                       \
        __builtin_amdgcn_sched_barrier(0);                                      \
        const int sn_ = ((s_) + 1) & 7;                                         \
        f4 e0 = *(const f4*)&ldsbuf[sn_][lane * 16];                            \
        f4 e1 = *(const f4*)&ldsbuf[sn_][1024 + lane * 16];                     \
        f4 e2 = *(const f4*)&ldsbuf[sn_][2048 + lane * 16];                     \
        int mk = *(const int*)&ldsbuf[s_][3072 + lane * 4];                     \
        if ((s_) == 0) {   /* renorm sample on 1-step-stale alpha */            \
            float rvf = (float)Bf[0].v[0];                                      \
            rshfl = __shfl(rvf, c);                                             \
        }                                                                       \
        f4 c0 = {0.f,0.f,0.f,0.f}, c1 = {0.f,0.f,0.f,0.f},                      \
           c2 = {0.f,0.f,0.f,0.f};                                              \
        c0 = mfma32(Afr[0][0].v, Bf[0].v, c0);                                  \
        c1 = mfma32(Afr[1][0].v, Bf[0].v, c1);                                  \
        c2 = mfma32(Afr[2][0].v, Bf[0].v, c2);                                  \
        c0 = mfma32(Afr[0][1].v, Bf[1].v, c0);                                  \
        c1 = mfma32(Afr[1][1].v, Bf[1].v, c1);                                  \
        c2 = mfma32(Afr[2][1].v, Bf[1].v, c2);                                  \
        c0 *= eem[0]; c1 *= eem[1]; c2 *= eem[2];                               \
        /* reads complete before this slot's restage write can land */          \
        asm volatile("s_waitcnt lgkmcnt(0)" ::: "memory");                      \
        bool keep = mk != 0;                                                    \
        unsigned adj = (unsigned)(n_cur * 0x00800080);   /* bf16 exp-field */   \
        n_cur = 0;                                                              \
        BU nb0, nb1;                                                            \
        nb0.v[0] = (__bf16)c0[0]; nb0.v[1] = (__bf16)c0[1];                     \
        nb0.v[2] = (__bf16)c0[2]; nb0.v[3] = (__bf16)c0[3];                     \
        nb0.v[4] = (__bf16)c1[0]; nb0.v[5] = (__bf16)c1[1];                     \
        nb0.v[6] = (__bf16)c1[2]; nb0.v[7] = (__bf16)c1[3];                     \
        nb1.v[0] = (__bf16)c2[0]; nb1.v[1] = (__bf16)c2[1];                     \
        nb1.v[2] = (__bf16)c2[2]; nb1.v[3] = (__bf16)c2[3];                     \
        nb1.v[4] = nb1.v[0]; nb1.v[5] = nb1.v[1];                               \
        nb1.v[6] = nb1.v[2]; nb1.v[7] = nb1.v[3];   /* pad rows, A=0 there */   \
        _Pragma("unroll")                                                       \
        for (int w = 0; w < 4; ++w) {                                           \
            Bf[0].u[w] = keep ? nb0.u[w] : (Bf[0].u[w] - adj);                  \
            Bf[1].u[w] = keep ? nb1.u[w] : (Bf[1].u[w] - adj);                  \
        }                                                                       \
        /* restage this slot with t+8 (clamped: keeps vmcnt count static) */    \
        {                                                                       \
            int tp_ = (t_) + PF;                                                \
            int tc_ = tp_ < S - 1 ? tp_ : S - 1;                                \
            STAGE(tc_, s_);                                                     \
        }                                                                       \
        float nrmf = 0.f;                                                       \
        if ((s_) == 0) {   /* finish renorm from early sample */                \
            int E_ = ((__float_as_int(rshfl) >> 23) & 255) - 127;               \
            int n_ = E_ + 30;              /* retarget alpha[0] to 2^-30 */     \
            offc += n_;  n_cur = n_;  nrmf = -(float)n_;                        \
        }                                                                       \
        _Pragma("unroll")                                                       \
        for (int e_ = 0; e_ < 4; ++e_) {                                        \
            eem[0][e_] = exp2f(fmaf(e0[e_], LOG2E, nrmf));                      \
            eem[1][e_] = exp2f(fmaf(e1[e_], LOG2E, nrmf));                      \
            eem[2][e_] = exp2f(fmaf(e2[e_], LOG2E, nrmf));                      \
        }                                                                       \
    }

    // main: t = 1 .. 504 (63 blocks of 8; slot = t&7 runs 1..7,0)
    for (int t0 = 1; t0 + 7 < S; t0 += PF) {
        STEP(1, t0)     STEP(2, t0 + 1) STEP(3, t0 + 2) STEP(4, t0 + 3)
        STEP(5, t0 + 4) STEP(6, t0 + 5) STEP(7, t0 + 6) STEP(0, t0 + 7)
    }
    // tail: t = 505 .. 511 (slots 1..7; staging clamped, results dead)
    STEP(1, 505) STEP(2, 506) STEP(3, 507) STEP(4, 508)
    STEP(5, 509) STEP(6, 510) STEP(7, 511)
#undef STEP
#undef STAGE

    // partition_c = offc*ln2 + ln( sum_k alpha[k][c] * exp(end[k]) )
    float val = 0.f;
    #pragma unroll
    for (int e = 0; e < 4; ++e) {
        val += (float)Bf[0].v[e]     * __expf(end_tr[4 * g + e]);
        val += (float)Bf[0].v[4 + e] * __expf(end_tr[16 + 4 * g + e]);
        val += (float)Bf[1].v[e]     * __expf(end_tr[32 + 4 * g + e]);
    }
    val += __shfl_xor(val, 16);
    val += __shfl_xor(val, 32);
    float part = (float)offc * LN2 + logf(val);

    // contrib replicated 4x over g -> sum all lanes, scale by 1/4
    float contrib = part - sc;
    #pragma unroll
    for (int off = 32; off > 0; off >>= 1) contrib += __shfl_xor(contrib, off);
    if (lane == 0) atomicAdd(out, contrib * 0.25f);
}

extern "C" void kernel_launch(void* const* d_in, const int* in_sizes, int n_in,
                              void* d_out, int out_size, void* d_ws, size_t ws_size,
                              hipStream_t stream) {
    const float* em       = (const float*)d_in[0];
    const int*   tags     = (const int*)d_in[1];
    const int*   mask     = (const int*)d_in[2];
    const float* trans    = (const float*)d_in[3];
    const float* start_tr = (const float*)d_in[4];
    const float* end_tr   = (const float*)d_in[5];
    float* out = (float*)d_out;

    zero_out<<<dim3(1), dim3(64), 0, stream>>>(out);
    crf_kernel<<<dim3(NBLK), dim3(64), 0, stream>>>(em, tags, mask, trans,
                                                    start_tr, end_tr, out);
}